// Round 1
// baseline (465.599 us; speedup 1.0000x reference)
//
#include <hip/hip_runtime.h>

#define N_NODES 100000
#define N_EDGES 20000
#define N_INC   800000
#define D_IN    256
#define D_H     16
#define D_OUT   40

__device__ __forceinline__ float atomAddF(float* p, float v) {
    // HW global_atomic_add_f32 (device scope). Values are normal-range fp32.
    return unsafeAtomicAdd(p, v);
}

// T[n][j] = sum_k H[n][k] * W1[k][j]   (thread per node, W1 via uniform/scalar loads)
__global__ __launch_bounds__(128) void gemm1_kernel(
    const float* __restrict__ H, const float* __restrict__ W1, float* __restrict__ T) {
    int n = blockIdx.x * 128 + threadIdx.x;
    if (n >= N_NODES) return;
    const float4* __restrict__ h4 = reinterpret_cast<const float4*>(H) + (size_t)n * (D_IN / 4);
    float acc[D_H];
#pragma unroll
    for (int j = 0; j < D_H; ++j) acc[j] = 0.f;
#pragma unroll 4
    for (int k4 = 0; k4 < D_IN / 4; ++k4) {
        float4 h = h4[k4];
        const float* __restrict__ w0 = W1 + (k4 * 4 + 0) * D_H;
        const float* __restrict__ w1 = W1 + (k4 * 4 + 1) * D_H;
        const float* __restrict__ w2 = W1 + (k4 * 4 + 2) * D_H;
        const float* __restrict__ w3 = W1 + (k4 * 4 + 3) * D_H;
#pragma unroll
        for (int j = 0; j < D_H; ++j)
            acc[j] += h.x * w0[j] + h.y * w1[j] + h.z * w2[j] + h.w * w3[j];
    }
    float4* out4 = reinterpret_cast<float4*>(T + (size_t)n * D_H);
    out4[0] = make_float4(acc[0], acc[1], acc[2], acc[3]);
    out4[1] = make_float4(acc[4], acc[5], acc[6], acc[7]);
    out4[2] = make_float4(acc[8], acc[9], acc[10], acc[11]);
    out4[3] = make_float4(acc[12], acc[13], acc[14], acc[15]);
}

// Node -> edge scatter at d=16: e_sum[e][j] += X[v][j]*w[v].
// 16 consecutive lanes share one incidence (coalesced 64B atomic groups).
// do_deg: lane j==0 also accumulates e_den/v_deg (layer-1 pass only).
__global__ __launch_bounds__(256) void scatterA_kernel(
    const int* __restrict__ ni, const int* __restrict__ ei, const float* __restrict__ w,
    const float* __restrict__ X, float* __restrict__ e_sum,
    float* e_den, float* v_deg, int do_deg) {
    int tid = blockIdx.x * 256 + threadIdx.x;
    int i = tid >> 4;
    if (i >= N_INC) return;
    int j = tid & 15;
    int v = ni[i];
    int e = ei[i];
    float wv = w[v];
    atomAddF(e_sum + e * D_H + j, X[v * D_H + j] * wv);
    if (do_deg && j == 0) {
        atomAddF(e_den + e, wv);
        atomAddF(v_deg + v, 1.0f);
    }
}

// reciprocals, once: inv_den = 1/max(e_den,1e-6); inv_deg = 1/max(v_deg,1)
__global__ __launch_bounds__(256) void recip_kernel(
    const float* __restrict__ e_den, const float* __restrict__ v_deg,
    float* __restrict__ inv_den, float* __restrict__ inv_deg) {
    int t = blockIdx.x * 256 + threadIdx.x;
    if (t < N_EDGES) inv_den[t] = 1.0f / fmaxf(e_den[t], 1e-6f);
    if (t < N_NODES) inv_deg[t] = 1.0f / fmaxf(v_deg[t], 1.0f);
}

// Edge -> node scatter at d=16 with fused edge-normalize:
// v_sum[v][j] += e_sum[e][j] * inv_den[e]
__global__ __launch_bounds__(256) void scatterB_kernel(
    const int* __restrict__ ni, const int* __restrict__ ei,
    const float* __restrict__ inv_den, const float* __restrict__ e_sum,
    float* __restrict__ v_sum) {
    int tid = blockIdx.x * 256 + threadIdx.x;
    int i = tid >> 4;
    if (i >= N_INC) return;
    int j = tid & 15;
    int v = ni[i];
    int e = ei[i];
    atomAddF(v_sum + v * D_H + j, e_sum[e * D_H + j] * inv_den[e]);
}

// x1 = relu(v_sum * inv_deg + b1)
__global__ __launch_bounds__(256) void finish1_kernel(
    const float* __restrict__ v_sum, const float* __restrict__ inv_deg,
    const float* __restrict__ b1, float* __restrict__ x1) {
    int t = blockIdx.x * 256 + threadIdx.x;
    if (t >= N_NODES * D_H) return;
    int n = t >> 4;
    int j = t & 15;
    x1[t] = fmaxf(v_sum[t] * inv_deg[n] + b1[j], 0.0f);
}

// out[n][:] = log_softmax( (v_sum2[n]*inv_deg[n]) @ W2 + b2 )
__global__ __launch_bounds__(256) void final_kernel(
    const float* __restrict__ v_sum, const float* __restrict__ inv_deg,
    const float* __restrict__ W2, const float* __restrict__ b2,
    float* __restrict__ out) {
    int n = blockIdx.x * 256 + threadIdx.x;
    if (n >= N_NODES) return;
    float s = inv_deg[n];
    const float4* vs4 = reinterpret_cast<const float4*>(v_sum + (size_t)n * D_H);
    float y[D_H];
    float4 a = vs4[0], b = vs4[1], c4 = vs4[2], d4 = vs4[3];
    y[0] = a.x * s;  y[1] = a.y * s;  y[2] = a.z * s;  y[3] = a.w * s;
    y[4] = b.x * s;  y[5] = b.y * s;  y[6] = b.z * s;  y[7] = b.w * s;
    y[8] = c4.x * s; y[9] = c4.y * s; y[10] = c4.z * s; y[11] = c4.w * s;
    y[12] = d4.x * s; y[13] = d4.y * s; y[14] = d4.z * s; y[15] = d4.w * s;

    float z[D_OUT];
#pragma unroll
    for (int c = 0; c < D_OUT; ++c) {
        float acc = b2[c];
#pragma unroll
        for (int j = 0; j < D_H; ++j) acc += y[j] * W2[j * D_OUT + c];
        z[c] = acc;
    }
    float m = z[0];
#pragma unroll
    for (int c = 1; c < D_OUT; ++c) m = fmaxf(m, z[c]);
    float se = 0.f;
#pragma unroll
    for (int c = 0; c < D_OUT; ++c) se += __expf(z[c] - m);
    float lse = m + __logf(se);
    float* o = out + (size_t)n * D_OUT;
#pragma unroll
    for (int c = 0; c < D_OUT; ++c) o[c] = z[c] - lse;
}

extern "C" void kernel_launch(void* const* d_in, const int* in_sizes, int n_in,
                              void* d_out, int out_size, void* d_ws, size_t ws_size,
                              hipStream_t stream) {
    const float* H  = (const float*)d_in[0];
    const float* w  = (const float*)d_in[1];
    const int*   ni = (const int*)d_in[2];
    const int*   ei = (const int*)d_in[3];
    const float* W1 = (const float*)d_in[4];
    const float* b1 = (const float*)d_in[5];
    const float* W2 = (const float*)d_in[6];
    const float* b2 = (const float*)d_in[7];
    float* out = (float*)d_out;
    float* ws  = (float*)d_ws;

    // workspace layout (floats)
    float* e_den   = ws + 0;        // 20000
    float* v_deg   = ws + 20000;    // 100000
    float* inv_den = ws + 120000;   // 20000
    float* inv_deg = ws + 140000;   // 100000
    float* e_sum1  = ws + 240000;   // 320000
    float* v_sum1  = ws + 560000;   // 1600000
    float* e_sum2  = ws + 2160000;  // 320000
    float* v_sum2  = ws + 2480000;  // 1600000
    float* T       = ws + 4080000;  // 1600000
    float* x1      = ws + 5680000;  // 1600000
    // total: 7,280,000 floats = 29.1 MB

    // zero accumulators (ws is poisoned 0xAA before every launch)
    hipMemsetAsync(e_den, 0, 120000 * sizeof(float), stream);          // e_den + v_deg
    hipMemsetAsync(e_sum1, 0, 3840000 * sizeof(float), stream);       // e_sum1..v_sum2

    gemm1_kernel<<<(N_NODES + 127) / 128, 128, 0, stream>>>(H, W1, T);

    const int scat_grid = (N_INC * D_H + 255) / 256;  // 50000
    scatterA_kernel<<<scat_grid, 256, 0, stream>>>(ni, ei, w, T, e_sum1, e_den, v_deg, 1);
    recip_kernel<<<(N_NODES + 255) / 256, 256, 0, stream>>>(e_den, v_deg, inv_den, inv_deg);
    scatterB_kernel<<<scat_grid, 256, 0, stream>>>(ni, ei, inv_den, e_sum1, v_sum1);
    finish1_kernel<<<(N_NODES * D_H + 255) / 256, 256, 0, stream>>>(v_sum1, inv_deg, b1, x1);

    scatterA_kernel<<<scat_grid, 256, 0, stream>>>(ni, ei, w, x1, e_sum2, e_den, v_deg, 0);
    scatterB_kernel<<<scat_grid, 256, 0, stream>>>(ni, ei, inv_den, e_sum2, v_sum2);

    final_kernel<<<(N_NODES + 255) / 256, 256, 0, stream>>>(v_sum2, inv_deg, W2, b2, out);
}